// Round 1
// baseline (139.516 us; speedup 1.0000x reference)
//
#include <hip/hip_runtime.h>
#include <stdint.h>

#define Bb 8
#define Ll 2048
#define Ss 2048
#define Dd 128
#define SCALE_LOG2E 92.33248261689366f  // 64 * log2(e)

typedef __attribute__((ext_vector_type(8))) short bf16x8;
typedef __attribute__((ext_vector_type(4))) float f32x4;

__device__ __forceinline__ unsigned f2bf_pack(float a, float b) {
  unsigned ua = __float_as_uint(a); ua += 0x7fffu + ((ua >> 16) & 1u);
  unsigned ub = __float_as_uint(b); ub += 0x7fffu + ((ub >> 16) & 1u);
  return (ua >> 16) | (ub & 0xffff0000u);
}

__device__ __forceinline__ void gl_lds16(const void* g, void* l) {
  __builtin_amdgcn_global_load_lds(
      (const __attribute__((address_space(1))) unsigned*)g,
      (__attribute__((address_space(3))) unsigned*)l, 16, 0, 0);
}

// ---------------- pre-pass 1: L2-normalize Q,K rows -> bf16 ----------------
extern "C" __global__ __launch_bounds__(256)
void nrm_kern(const float* __restrict__ Q, const float* __restrict__ K,
              unsigned short* __restrict__ Qn, unsigned short* __restrict__ Kn) {
  const int lane = threadIdx.x & 63;
  int row = (blockIdx.x << 2) + (threadIdx.x >> 6);  // one row per wave
  int r = row;
  const float* src = Q; unsigned short* dst = Qn;
  if (row >= Bb * Ll) { r = row - Bb * Ll; src = K; dst = Kn; }
  float2 f = *(const float2*)(src + (size_t)r * Dd + lane * 2);
  float ss = f.x * f.x + f.y * f.y;
#pragma unroll
  for (int m = 1; m < 64; m <<= 1) ss += __shfl_xor(ss, m, 64);
  float inv = 1.0f / fmaxf(sqrtf(ss), 1e-12f);
  *(unsigned*)(dst + (size_t)r * Dd + lane * 2) = f2bf_pack(f.x * inv, f.y * inv);
}

// ---------------- pre-pass 2: V [B][S][D] f32 -> Vt [B][D][S] bf16 ----------
#define TRS 138  // ushort stride per s-row in LDS tile (64+pad keeps banks spread)
extern "C" __global__ __launch_bounds__(256)
void vtr_kern(const float* __restrict__ V, unsigned short* __restrict__ Vt) {
  __shared__ unsigned short T[64 * TRS];
  const int t = threadIdx.x;
  const int b = blockIdx.x & 7, sb = blockIdx.x >> 3;  // 64-row s window
  const int d4 = t & 31, sr = t >> 5;
#pragma unroll
  for (int p = 0; p < 8; ++p) {
    int sl = p * 8 + sr;
    float4 v = *(const float4*)(V + ((size_t)(b * Ss + sb * 64 + sl)) * Dd + d4 * 4);
    *(unsigned*)&T[sl * TRS + d4 * 4]     = f2bf_pack(v.x, v.y);
    *(unsigned*)&T[sl * TRS + d4 * 4 + 2] = f2bf_pack(v.z, v.w);
  }
  __syncthreads();
  const int oct = t & 7, dbase = t >> 3;
#pragma unroll
  for (int p = 0; p < 4; ++p) {
    int d = p * 32 + dbase;
    unsigned u[4];
#pragma unroll
    for (int k = 0; k < 4; ++k) {
      unsigned lo = T[(oct * 8 + 2 * k) * TRS + d];
      unsigned hi = T[(oct * 8 + 2 * k + 1) * TRS + d];
      u[k] = lo | (hi << 16);
    }
    *(uint4*)(Vt + ((size_t)(b * Dd + d)) * Ss + sb * 64 + oct * 8) =
        make_uint4(u[0], u[1], u[2], u[3]);
  }
}

// ---------------- main fused attention ----------------
// grid 256: blockIdx = qt*8 + b  (batch -> XCD for L2 residency)
// WG = 4 waves, each owns 16 Q rows. S-tile N=128, double-buffered LDS.
extern "C" __global__ __launch_bounds__(256, 1)
void attn_kern(const unsigned short* __restrict__ Qn,
               const unsigned short* __restrict__ Kn,
               const unsigned short* __restrict__ Vt,
               float* __restrict__ Out) {
  __shared__ unsigned short Kl[2][32 * 512];  // fragment-major: slot*1024B + lane*16B
  __shared__ unsigned short Vl[2][32 * 512];
  __shared__ unsigned short Pl[4][2048];      // per-wave private P^T (B-frag layout)
  const int tid = threadIdx.x, wv = tid >> 6, lane = tid & 63;
  const int q = lane >> 4, lm = lane & 15;
  const int b = blockIdx.x & 7, qt = blockIdx.x >> 3;
  const int mrow = qt * 64 + wv * 16 + lm;

  // Q^T B-fragments, kept in registers for the whole kernel
  const unsigned short* Qrow = Qn + ((size_t)(b * Ll + mrow)) * Dd;
  bf16x8 qf[4];
#pragma unroll
  for (int kt = 0; kt < 4; ++kt)
    qf[kt] = *(const bf16x8*)(Qrow + kt * 32 + q * 8);

  const unsigned short* Kb = Kn + (size_t)b * Ss * Dd;
  const unsigned short* Vb = Vt + (size_t)b * Dd * Ss;

  f32x4 o[8];
#pragma unroll
  for (int i = 0; i < 8; ++i) o[i] = (f32x4){0.f, 0.f, 0.f, 0.f};
  float mrun = -1e30f, lrun = 0.f;

  // prologue: stage tile 0 into buffer 0 (wave wv stages kt/ks == wv, 8 stiles/dtiles)
#pragma unroll
  for (int i = 0; i < 8; ++i) {
    gl_lds16(Kb + ((size_t)(i * 16 + lm)) * Dd + wv * 32 + q * 8,
             &Kl[0][(i * 4 + wv) * 512]);
    gl_lds16(Vb + ((size_t)(i * 16 + lm)) * Ss + wv * 32 + q * 8,
             &Vl[0][(i * 4 + wv) * 512]);
  }

#pragma unroll 1
  for (int it = 0; it < 16; ++it) {
    __syncthreads();  // drains vmcnt: cur buffer staged; prev buffer reads done
    const int cur = it & 1, nxt = cur ^ 1;
    if (it + 1 < 16) {  // prefetch next tile into other buffer during compute
#pragma unroll
      for (int i = 0; i < 8; ++i) {
        gl_lds16(Kb + ((size_t)((it + 1) * 128 + i * 16 + lm)) * Dd + wv * 32 + q * 8,
                 &Kl[nxt][(i * 4 + wv) * 512]);
        gl_lds16(Vb + ((size_t)(i * 16 + lm)) * Ss + (it + 1) * 128 + wv * 32 + q * 8,
                 &Vl[nxt][(i * 4 + wv) * 512]);
      }
    }
    // S^T = K · Q^T  (M=s, N=m, K=d)
    f32x4 st[8];
#pragma unroll
    for (int s8 = 0; s8 < 8; ++s8) {
      f32x4 acc = (f32x4){0.f, 0.f, 0.f, 0.f};
#pragma unroll
      for (int kt = 0; kt < 4; ++kt) {
        bf16x8 kf = *(const bf16x8*)&Kl[cur][(s8 * 4 + kt) * 512 + lane * 8];
        acc = __builtin_amdgcn_mfma_f32_16x16x32_bf16(kf, qf[kt], acc, 0, 0, 0);
      }
      st[s8] = acc;
    }
    // online softmax over s (rows of S^T): in-lane max + xor16 + xor32
    float vmax = st[0][0];
#pragma unroll
    for (int s8 = 0; s8 < 8; ++s8)
      vmax = fmaxf(vmax, fmaxf(fmaxf(st[s8][0], st[s8][1]), fmaxf(st[s8][2], st[s8][3])));
    vmax = fmaxf(vmax, __shfl_xor(vmax, 16, 64));
    vmax = fmaxf(vmax, __shfl_xor(vmax, 32, 64));
    const float mnew = fmaxf(mrun, vmax * SCALE_LOG2E);
    const float alpha = __builtin_amdgcn_exp2f(mrun - mnew);
    mrun = mnew;
    float ls = 0.f;
#pragma unroll
    for (int s8 = 0; s8 < 8; ++s8) {
      float p0 = __builtin_amdgcn_exp2f(st[s8][0] * SCALE_LOG2E - mnew);
      float p1 = __builtin_amdgcn_exp2f(st[s8][1] * SCALE_LOG2E - mnew);
      float p2 = __builtin_amdgcn_exp2f(st[s8][2] * SCALE_LOG2E - mnew);
      float p3 = __builtin_amdgcn_exp2f(st[s8][3] * SCALE_LOG2E - mnew);
      ls += (p0 + p1) + (p2 + p3);
      // scatter C-layout -> B-operand layout:  s = s8*16 + q*4 + reg
      int off = ((s8 >> 1) * 64 + ((s8 * 2 + (q >> 1)) & 3) * 16 + lm) * 16 + (q & 1) * 8;
      *(uint2*)((char*)&Pl[wv][0] + off) = make_uint2(f2bf_pack(p0, p1), f2bf_pack(p2, p3));
    }
    lrun = lrun * alpha + ls;
#pragma unroll
    for (int i = 0; i < 8; ++i) {
      o[i][0] *= alpha; o[i][1] *= alpha; o[i][2] *= alpha; o[i][3] *= alpha;
    }
    // O^T += V^T · P^T  (M=d, N=m, K=s) ; wave-private P, no barrier needed
#pragma unroll
    for (int ks = 0; ks < 4; ++ks) {
      bf16x8 pf = *(const bf16x8*)&Pl[wv][ks * 512 + lane * 8];
#pragma unroll
      for (int d8 = 0; d8 < 8; ++d8) {
        bf16x8 vf = *(const bf16x8*)&Vl[cur][(d8 * 4 + ks) * 512 + lane * 8];
        o[d8] = __builtin_amdgcn_mfma_f32_16x16x32_bf16(vf, pf, o[d8], 0, 0, 0);
      }
    }
  }
  // epilogue: finish l reduction, normalize, store fp32
  float lt = lrun;
  lt += __shfl_xor(lt, 16, 64);
  lt += __shfl_xor(lt, 32, 64);
  const float inv = 1.0f / lt;
  float* Orow = Out + ((size_t)(b * Ll + mrow)) * Dd;
#pragma unroll
  for (int d8 = 0; d8 < 8; ++d8) {
    float4 r;
    r.x = o[d8][0] * inv; r.y = o[d8][1] * inv;
    r.z = o[d8][2] * inv; r.w = o[d8][3] * inv;
    *(float4*)(Orow + d8 * 16 + q * 4) = r;
  }
}

extern "C" void kernel_launch(void* const* d_in, const int* in_sizes, int n_in,
                              void* d_out, int out_size, void* d_ws, size_t ws_size,
                              hipStream_t stream) {
  const float* Q = (const float*)d_in[0];
  const float* K = (const float*)d_in[1];
  const float* V = (const float*)d_in[2];
  float* Out = (float*)d_out;
  unsigned short* Qn = (unsigned short*)d_ws;                 // 4 MiB
  unsigned short* Kn = Qn + (size_t)Bb * Ll * Dd;             // 4 MiB
  unsigned short* Vt = Kn + (size_t)Bb * Ss * Dd;             // 4 MiB
  hipLaunchKernelGGL(nrm_kern, dim3((Bb * (Ll + Ss)) / 4), dim3(256), 0, stream, Q, K, Qn, Kn);
  hipLaunchKernelGGL(vtr_kern, dim3(Bb * (Ss / 64)), dim3(256), 0, stream, V, Vt);
  hipLaunchKernelGGL(attn_kern, dim3(Bb * (Ll / 64)), dim3(256), 0, stream, Qn, Kn, Vt, Out);
}

// Round 2
// 113.627 us; speedup vs baseline: 1.2278x; 1.2278x over previous
//
#include <hip/hip_runtime.h>
#include <stdint.h>

#define Bb 8
#define Ll 2048
#define Ss 2048
#define Dd 128
#define NSB 4
#define SCHUNK 512
#define NROWS 16384  // Bb*Ll == Bb*Ss
#define SCALE_LOG2E 92.33248261689366f  // 64 * log2(e)

typedef __attribute__((ext_vector_type(8))) short bf16x8;
typedef __attribute__((ext_vector_type(4))) float f32x4;
typedef __attribute__((ext_vector_type(16))) float f32x16;
typedef __attribute__((ext_vector_type(4))) unsigned u32x4;

__device__ __forceinline__ unsigned f2bf_pack(float a, float b) {
  unsigned ua = __float_as_uint(a); ua += 0x7fffu + ((ua >> 16) & 1u);
  unsigned ub = __float_as_uint(b); ub += 0x7fffu + ((ub >> 16) & 1u);
  return (ua >> 16) | (ub & 0xffff0000u);
}

__device__ __forceinline__ void gl_lds16(const void* g, void* l) {
  __builtin_amdgcn_global_load_lds(
      (const __attribute__((address_space(1))) unsigned*)g,
      (__attribute__((address_space(3))) unsigned*)l, 16, 0, 0);
}

// ---------------- fused pre-pass: Q/K row-normalize -> bf16, V -> V^T bf16 ---
#define TRS 138
extern "C" __global__ __launch_bounds__(256)
void prep_kern(const float* __restrict__ Q, const float* __restrict__ K,
               const float* __restrict__ V,
               unsigned short* __restrict__ Qn, unsigned short* __restrict__ Kn,
               unsigned short* __restrict__ Vt) {
  __shared__ unsigned short T[32 * TRS];
  const int t = threadIdx.x;
  const int bid = blockIdx.x;
  if (bid < 8192) {  // Q/K row normalization, one row per wave
    const int lane = t & 63;
    int row = (bid << 2) + (t >> 6);
    int r = row;
    const float* src = Q; unsigned short* dst = Qn;
    if (row >= NROWS) { r = row - NROWS; src = K; dst = Kn; }
    float2 f = *(const float2*)(src + (size_t)r * Dd + lane * 2);
    float ss = f.x * f.x + f.y * f.y;
#pragma unroll
    for (int m = 1; m < 64; m <<= 1) ss += __shfl_xor(ss, m, 64);
    float inv = 1.0f / fmaxf(sqrtf(ss), 1e-12f);
    *(unsigned*)(dst + (size_t)r * Dd + lane * 2) = f2bf_pack(f.x * inv, f.y * inv);
  } else {  // V transpose: 32-s-row window per block
    const int vb = bid - 8192;
    const int b = vb & 7, sw = vb >> 3;
    const int d4 = t & 31, sr = t >> 5;
#pragma unroll
    for (int p = 0; p < 4; ++p) {
      int sl = p * 8 + sr;
      float4 v = *(const float4*)(V + ((size_t)(b * Ss + sw * 32 + sl)) * Dd + d4 * 4);
      *(unsigned*)&T[sl * TRS + d4 * 4]     = f2bf_pack(v.x, v.y);
      *(unsigned*)&T[sl * TRS + d4 * 4 + 2] = f2bf_pack(v.z, v.w);
    }
    __syncthreads();
    const int so = t & 3, db = t >> 2;
#pragma unroll
    for (int p = 0; p < 2; ++p) {
      int d = p * 64 + db;
      unsigned u[4];
#pragma unroll
      for (int k = 0; k < 4; ++k) {
        unsigned lo = T[(so * 8 + 2 * k) * TRS + d];
        unsigned hi = T[(so * 8 + 2 * k + 1) * TRS + d];
        u[k] = lo | (hi << 16);
      }
      *(uint4*)(Vt + ((size_t)(b * Dd + d)) * Ss + sw * 32 + so * 8) =
          make_uint4(u[0], u[1], u[2], u[3]);
    }
  }
}

// ---------------- main fused attention (S-split flash) ----------------
// grid 512: gid = qt*32 + (b*4 + sb); WG = 4 waves, each owns 32 q-rows.
// S-chunk = 512, tile 64, double-buffered LDS (64 KB) -> 2 WG/CU.
extern "C" __global__ __launch_bounds__(256, 2)
void attn_kern(const unsigned short* __restrict__ Qn,
               const unsigned short* __restrict__ Kn,
               const unsigned short* __restrict__ Vt,
               unsigned short* __restrict__ Op,
               float* __restrict__ Mp, float* __restrict__ Lp) {
  __shared__ unsigned short Kl[2][16 * 512];  // 16 slots * 1KB, fragment-major
  __shared__ unsigned short Vl[2][16 * 512];
  const int tid = threadIdx.x, wv = tid >> 6, lane = tid & 63;
  const int lm = lane & 31, h = lane >> 5;
  const int gid = blockIdx.x;
  const int grp = gid & 31, qt = gid >> 5;
  const int b = grp >> 2, sb = grp & 3;
  const int sbase = sb * SCHUNK;
  const int qrow = qt * 128 + wv * 32 + lm;

  // Q B-fragments (k = d): held in registers for whole kernel
  const unsigned short* Qrow = Qn + ((size_t)(b * Ll + qrow)) * Dd;
  bf16x8 qf[8];
#pragma unroll
  for (int kt = 0; kt < 8; ++kt)
    qf[kt] = *(const bf16x8*)(Qrow + kt * 16 + h * 8);

  const unsigned short* Kb = Kn + (size_t)b * Ss * Dd;
  const unsigned short* Vb = Vt + (size_t)b * Dd * Ss;

  f32x16 o[4];
#pragma unroll
  for (int i = 0; i < 4; ++i)
#pragma unroll
    for (int r = 0; r < 16; ++r) o[i][r] = 0.f;

  auto stage = [&](int it, int buf) {
    const int s0 = sbase + it * 64;
#pragma unroll
    for (int i = 0; i < 4; ++i) {
      const int ks = wv * 4 + i;  // slot = sblk*8 + kt
      gl_lds16(Kb + (size_t)(s0 + (ks >> 3) * 32 + lm) * Dd + (ks & 7) * 16 + h * 8,
               &Kl[buf][ks * 512]);
    }
#pragma unroll
    for (int i = 0; i < 4; ++i) {
      const int vs = wv * 4 + i;  // slot = dblk*4 + t
      gl_lds16(Vb + (size_t)((vs >> 2) * 32 + lm) * Ss + s0 + (vs & 3) * 16 + h * 8,
               &Vl[buf][vs * 512]);
    }
  };
  stage(0, 0);

  float mrun = -1e30f, lrun = 0.f;

#pragma unroll 1
  for (int it = 0; it < 8; ++it) {
    __syncthreads();  // drains vmcnt: cur staged, prev reads done
    const int cur = it & 1;
    if (it + 1 < 8) stage(it + 1, cur ^ 1);

    // S^T = K · Q^T  (M=s 2x32, N=m 32, K=d 8x16)
    f32x16 st[2];
#pragma unroll
    for (int sblk = 0; sblk < 2; ++sblk) {
      f32x16 acc;
#pragma unroll
      for (int r = 0; r < 16; ++r) acc[r] = 0.f;
#pragma unroll
      for (int kt = 0; kt < 8; ++kt) {
        bf16x8 kf = *(const bf16x8*)&Kl[cur][(sblk * 8 + kt) * 512 + lane * 8];
        acc = __builtin_amdgcn_mfma_f32_32x32x16_bf16(kf, qf[kt], acc, 0, 0, 0);
      }
      st[sblk] = acc;
    }

    // online softmax over s for each m=lane&31
    float vmax = st[0][0];
#pragma unroll
    for (int r = 0; r < 16; ++r) vmax = fmaxf(vmax, fmaxf(st[0][r], st[1][r]));
    vmax = fmaxf(vmax, __shfl_xor(vmax, 32, 64));
    const float mnew = fmaxf(mrun, vmax * SCALE_LOG2E);
    const float alpha = __builtin_amdgcn_exp2f(mrun - mnew);
    mrun = mnew;
#pragma unroll
    for (int i = 0; i < 4; ++i)
#pragma unroll
      for (int r = 0; r < 16; ++r) o[i][r] *= alpha;

    float ls = 0.f;
#pragma unroll
    for (int t = 0; t < 4; ++t) {  // 16-s block; P B-frag built via xor-32 shuffles
      float p[8];
#pragma unroll
      for (int j = 0; j < 8; ++j) {
        p[j] = __builtin_amdgcn_exp2f(st[t >> 1][(t & 1) * 8 + j] * SCALE_LOG2E - mnew);
        ls += p[j];
      }
      unsigned u0 = f2bf_pack(p[0], p[1]), u1 = f2bf_pack(p[2], p[3]);
      unsigned u2 = f2bf_pack(p[4], p[5]), u3 = f2bf_pack(p[6], p[7]);
      unsigned s0 = (unsigned)__shfl_xor((int)u0, 32, 64);
      unsigned s1 = (unsigned)__shfl_xor((int)u1, 32, 64);
      unsigned s2 = (unsigned)__shfl_xor((int)u2, 32, 64);
      unsigned s3 = (unsigned)__shfl_xor((int)u3, 32, 64);
      u32x4 fr;
      fr.x = h ? s2 : u0;  // j0j1
      fr.y = h ? s3 : u1;  // j2j3
      fr.z = h ? u2 : s0;  // j4j5
      fr.w = h ? u3 : s1;  // j6j7
      bf16x8 pf = __builtin_bit_cast(bf16x8, fr);
      // O^T += V^T · P^T  (M=d 4x32, N=m 32, K=s 16)
#pragma unroll
      for (int dblk = 0; dblk < 4; ++dblk) {
        bf16x8 vf = *(const bf16x8*)&Vl[cur][(dblk * 4 + t) * 512 + lane * 8];
        o[dblk] = __builtin_amdgcn_mfma_f32_32x32x16_bf16(vf, pf, o[dblk], 0, 0, 0);
      }
    }
    lrun = lrun * alpha + ls;
  }

  // epilogue: partial (unnormalized) O in bf16 + per-row (m, l)
  const float lt = lrun + __shfl_xor(lrun, 32, 64);
  unsigned short* Ob = Op + ((size_t)sb * NROWS + b * Ll + qrow) * Dd;
#pragma unroll
  for (int dblk = 0; dblk < 4; ++dblk)
#pragma unroll
    for (int g = 0; g < 4; ++g) {
      uint2 w;
      w.x = f2bf_pack(o[dblk][g * 4 + 0], o[dblk][g * 4 + 1]);
      w.y = f2bf_pack(o[dblk][g * 4 + 2], o[dblk][g * 4 + 3]);
      *(uint2*)(Ob + dblk * 32 + g * 8 + h * 4) = w;  // d = 32*dblk + 8*g + 4*h
    }
  if (h == 0) {
    Mp[sb * NROWS + b * Ll + qrow] = mrun;
    Lp[sb * NROWS + b * Ll + qrow] = lt;
  }
}

// ---------------- combine the NSB S-chunk partials ----------------
extern "C" __global__ __launch_bounds__(256)
void comb_kern(const unsigned short* __restrict__ Op, const float* __restrict__ Mp,
               const float* __restrict__ Lp, float* __restrict__ Out) {
  const int idx = blockIdx.x * 256 + threadIdx.x;  // one thread per 4 d
  const int row = idx >> 5;
  const int dof = (idx & 31) * 4;
  float m[NSB], w[NSB];
  float M = -1e30f;
#pragma unroll
  for (int s = 0; s < NSB; ++s) { m[s] = Mp[s * NROWS + row]; M = fmaxf(M, m[s]); }
  float den = 0.f;
#pragma unroll
  for (int s = 0; s < NSB; ++s) {
    w[s] = __builtin_amdgcn_exp2f(m[s] - M);
    den += Lp[s * NROWS + row] * w[s];
  }
  float a0 = 0.f, a1 = 0.f, a2 = 0.f, a3 = 0.f;
#pragma unroll
  for (int s = 0; s < NSB; ++s) {
    uint2 v = *(const uint2*)(Op + ((size_t)s * NROWS + row) * Dd + dof);
    a0 += w[s] * __uint_as_float(v.x << 16);
    a1 += w[s] * __uint_as_float(v.x & 0xffff0000u);
    a2 += w[s] * __uint_as_float(v.y << 16);
    a3 += w[s] * __uint_as_float(v.y & 0xffff0000u);
  }
  const float inv = 1.f / den;
  float4 r; r.x = a0 * inv; r.y = a1 * inv; r.z = a2 * inv; r.w = a3 * inv;
  *(float4*)(Out + (size_t)row * Dd + dof) = r;
}

extern "C" void kernel_launch(void* const* d_in, const int* in_sizes, int n_in,
                              void* d_out, int out_size, void* d_ws, size_t ws_size,
                              hipStream_t stream) {
  const float* Q = (const float*)d_in[0];
  const float* K = (const float*)d_in[1];
  const float* V = (const float*)d_in[2];
  float* Out = (float*)d_out;
  unsigned short* Qn = (unsigned short*)d_ws;                  // 4 MiB
  unsigned short* Kn = Qn + (size_t)NROWS * Dd;                // 4 MiB
  unsigned short* Vt = Kn + (size_t)NROWS * Dd;                // 4 MiB
  unsigned short* Op = Vt + (size_t)Bb * Dd * Ss;              // 16 MiB (bf16 partials)
  float* Mp = (float*)(Op + (size_t)NSB * NROWS * Dd);         // 256 KiB
  float* Lp = Mp + (size_t)NSB * NROWS;                        // 256 KiB
  hipLaunchKernelGGL(prep_kern, dim3(8192 + 512), dim3(256), 0, stream, Q, K, V, Qn, Kn, Vt);
  hipLaunchKernelGGL(attn_kern, dim3(512), dim3(256), 0, stream, Qn, Kn, Vt, Op, Mp, Lp);
  hipLaunchKernelGGL(comb_kern, dim3(2048), dim3(256), 0, stream, Op, Mp, Lp, Out);
}

// Round 3
// 110.831 us; speedup vs baseline: 1.2588x; 1.0252x over previous
//
#include <hip/hip_runtime.h>
#include <stdint.h>

#define Bb 8
#define Ll 2048
#define Ss 2048
#define Dd 128
#define NSB 4
#define SCHUNK 512
#define NROWS 16384  // Bb*Ll == Bb*Ss
#define SCALE_LOG2E 92.33248261689366f  // 64 * log2(e); also the fixed softmax max

typedef __attribute__((ext_vector_type(8))) short bf16x8;
typedef __attribute__((ext_vector_type(16))) float f32x16;
typedef __attribute__((ext_vector_type(4))) unsigned u32x4;

__device__ __forceinline__ unsigned f2bf_pack(float a, float b) {
  unsigned ua = __float_as_uint(a); ua += 0x7fffu + ((ua >> 16) & 1u);
  unsigned ub = __float_as_uint(b); ub += 0x7fffu + ((ub >> 16) & 1u);
  return (ua >> 16) | (ub & 0xffff0000u);
}

__device__ __forceinline__ unsigned pkbf(float a, float b) {
#if __has_builtin(__builtin_amdgcn_cvt_pk_bf16_f32)
  auto r = __builtin_amdgcn_cvt_pk_bf16_f32(a, b);  // gfx950 v_cvt_pk_bf16_f32
  return __builtin_bit_cast(unsigned, r);
#else
  return f2bf_pack(a, b);
#endif
}

__device__ __forceinline__ void gl_lds16(const void* g, void* l) {
  __builtin_amdgcn_global_load_lds(
      (const __attribute__((address_space(1))) unsigned*)g,
      (__attribute__((address_space(3))) unsigned*)l, 16, 0, 0);
}

// ---------------- fused pre-pass: Q/K row-normalize -> bf16, V -> V^T bf16 ---
#define TRS 138
extern "C" __global__ __launch_bounds__(256)
void prep_kern(const float* __restrict__ Q, const float* __restrict__ K,
               const float* __restrict__ V,
               unsigned short* __restrict__ Qn, unsigned short* __restrict__ Kn,
               unsigned short* __restrict__ Vt) {
  __shared__ unsigned short T[32 * TRS];
  const int t = threadIdx.x;
  const int bid = blockIdx.x;
  if (bid < 8192) {  // Q/K row normalization, one row per wave
    const int lane = t & 63;
    int row = (bid << 2) + (t >> 6);
    int r = row;
    const float* src = Q; unsigned short* dst = Qn;
    if (row >= NROWS) { r = row - NROWS; src = K; dst = Kn; }
    float2 f = *(const float2*)(src + (size_t)r * Dd + lane * 2);
    float ss = f.x * f.x + f.y * f.y;
#pragma unroll
    for (int m = 1; m < 64; m <<= 1) ss += __shfl_xor(ss, m, 64);
    float inv = 1.0f / fmaxf(sqrtf(ss), 1e-12f);
    *(unsigned*)(dst + (size_t)r * Dd + lane * 2) = pkbf(f.x * inv, f.y * inv);
  } else {  // V transpose: 32-s-row window per block
    const int vb = bid - 8192;
    const int b = vb & 7, sw = vb >> 3;
    const int d4 = t & 31, sr = t >> 5;
#pragma unroll
    for (int p = 0; p < 4; ++p) {
      int sl = p * 8 + sr;
      float4 v = *(const float4*)(V + ((size_t)(b * Ss + sw * 32 + sl)) * Dd + d4 * 4);
      *(unsigned*)&T[sl * TRS + d4 * 4]     = pkbf(v.x, v.y);
      *(unsigned*)&T[sl * TRS + d4 * 4 + 2] = pkbf(v.z, v.w);
    }
    __syncthreads();
    const int so = t & 3, db = t >> 2;
#pragma unroll
    for (int p = 0; p < 2; ++p) {
      int d = p * 64 + db;
      unsigned u[4];
#pragma unroll
      for (int k = 0; k < 4; ++k) {
        unsigned lo = T[(so * 8 + 2 * k) * TRS + d];
        unsigned hi = T[(so * 8 + 2 * k + 1) * TRS + d];
        u[k] = lo | (hi << 16);
      }
      *(uint4*)(Vt + ((size_t)(b * Dd + d)) * Ss + sw * 32 + so * 8) =
          make_uint4(u[0], u[1], u[2], u[3]);
    }
  }
}

// ---------------- main fused attention (S-split flash, FIXED softmax max) ----
// grid 512: gid = qt*32 + (b*4 + sb); WG = 4 waves, each owns 32 q-rows.
// S-chunk = 512, tile 64, double-buffered LDS (64 KB) -> 2 WG/CU.
// Q,K are L2-normalized => logit*log2e <= SCALE_LOG2E, so softmax uses a
// compile-time max: no running max, no alpha, no o-rescale, no max shuffles.
extern "C" __global__ __launch_bounds__(256, 2)
void attn_kern(const unsigned short* __restrict__ Qn,
               const unsigned short* __restrict__ Kn,
               const unsigned short* __restrict__ Vt,
               unsigned short* __restrict__ Op,
               float* __restrict__ Lp) {
  __shared__ unsigned short Kl[2][16 * 512];  // 16 slots * 1KB, fragment-major
  __shared__ unsigned short Vl[2][16 * 512];
  const int tid = threadIdx.x, wv = tid >> 6, lane = tid & 63;
  const int lm = lane & 31, h = lane >> 5;
  const int gid = blockIdx.x;
  const int grp = gid & 31, qt = gid >> 5;
  const int b = grp >> 2, sb = grp & 3;
  const int sbase = sb * SCHUNK;
  const int qrow = qt * 128 + wv * 32 + lm;

  // Q B-fragments (k = d): held in registers for whole kernel
  const unsigned short* Qrow = Qn + ((size_t)(b * Ll + qrow)) * Dd;
  bf16x8 qf[8];
#pragma unroll
  for (int kt = 0; kt < 8; ++kt)
    qf[kt] = *(const bf16x8*)(Qrow + kt * 16 + h * 8);

  const unsigned short* Kb = Kn + (size_t)b * Ss * Dd;
  const unsigned short* Vb = Vt + (size_t)b * Dd * Ss;

  f32x16 o[4];
#pragma unroll
  for (int i = 0; i < 4; ++i)
#pragma unroll
    for (int r = 0; r < 16; ++r) o[i][r] = 0.f;

  auto stage = [&](int it, int buf) {
    const int s0 = sbase + it * 64;
#pragma unroll
    for (int i = 0; i < 4; ++i) {
      const int ks = wv * 4 + i;  // slot = sblk*8 + kt
      gl_lds16(Kb + (size_t)(s0 + (ks >> 3) * 32 + lm) * Dd + (ks & 7) * 16 + h * 8,
               &Kl[buf][ks * 512]);
    }
#pragma unroll
    for (int i = 0; i < 4; ++i) {
      const int vs = wv * 4 + i;  // slot = dblk*4 + t
      gl_lds16(Vb + (size_t)((vs >> 2) * 32 + lm) * Ss + s0 + (vs & 3) * 16 + h * 8,
               &Vl[buf][vs * 512]);
    }
  };
  stage(0, 0);

  float lrun = 0.f;

#pragma unroll 1
  for (int it = 0; it < 8; ++it) {
    __syncthreads();  // drains vmcnt: cur staged, prev reads done
    const int cur = it & 1;
    if (it + 1 < 8) stage(it + 1, cur ^ 1);

    // S^T = K · Q^T  (M=s 2x32, N=m 32, K=d 8x16)
    f32x16 st[2];
#pragma unroll
    for (int sblk = 0; sblk < 2; ++sblk) {
      f32x16 acc;
#pragma unroll
      for (int r = 0; r < 16; ++r) acc[r] = 0.f;
#pragma unroll
      for (int kt = 0; kt < 8; ++kt) {
        bf16x8 kf = *(const bf16x8*)&Kl[cur][(sblk * 8 + kt) * 512 + lane * 8];
        acc = __builtin_amdgcn_mfma_f32_32x32x16_bf16(kf, qf[kt], acc, 0, 0, 0);
      }
      st[sblk] = acc;
    }

    // fixed-max softmax: p = 2^(st*SC - SC), elementwise independent
    float ls = 0.f;
#pragma unroll
    for (int t = 0; t < 4; ++t) {  // 16-s block; P B-frag built via xor-32 shuffles
      float p[8];
#pragma unroll
      for (int j = 0; j < 8; ++j)
        p[j] = __builtin_amdgcn_exp2f(
            __builtin_fmaf(st[t >> 1][(t & 1) * 8 + j], SCALE_LOG2E, -SCALE_LOG2E));
      ls += ((p[0] + p[1]) + (p[2] + p[3])) + ((p[4] + p[5]) + (p[6] + p[7]));
      unsigned u0 = pkbf(p[0], p[1]), u1 = pkbf(p[2], p[3]);
      unsigned u2 = pkbf(p[4], p[5]), u3 = pkbf(p[6], p[7]);
      unsigned s0 = (unsigned)__shfl_xor((int)u0, 32, 64);
      unsigned s1 = (unsigned)__shfl_xor((int)u1, 32, 64);
      unsigned s2 = (unsigned)__shfl_xor((int)u2, 32, 64);
      unsigned s3 = (unsigned)__shfl_xor((int)u3, 32, 64);
      u32x4 fr;
      fr.x = h ? s2 : u0;  // j0j1
      fr.y = h ? s3 : u1;  // j2j3
      fr.z = h ? u2 : s0;  // j4j5
      fr.w = h ? u3 : s1;  // j6j7
      bf16x8 pf = __builtin_bit_cast(bf16x8, fr);
      // O^T += V^T · P^T  (M=d 4x32, N=m 32, K=s 16)
#pragma unroll
      for (int dblk = 0; dblk < 4; ++dblk) {
        bf16x8 vf = *(const bf16x8*)&Vl[cur][(dblk * 4 + t) * 512 + lane * 8];
        o[dblk] = __builtin_amdgcn_mfma_f32_32x32x16_bf16(vf, pf, o[dblk], 0, 0, 0);
      }
    }
    lrun += ls;
  }

  // epilogue: partial (unnormalized) O in bf16 + per-row l (shared fixed max)
  const float lt = lrun + __shfl_xor(lrun, 32, 64);
  unsigned short* Ob = Op + ((size_t)sb * NROWS + b * Ll + qrow) * Dd;
#pragma unroll
  for (int dblk = 0; dblk < 4; ++dblk)
#pragma unroll
    for (int g = 0; g < 4; ++g) {
      uint2 w;
      w.x = pkbf(o[dblk][g * 4 + 0], o[dblk][g * 4 + 1]);
      w.y = pkbf(o[dblk][g * 4 + 2], o[dblk][g * 4 + 3]);
      *(uint2*)(Ob + dblk * 32 + g * 8 + h * 4) = w;  // d = 32*dblk + 8*g + 4*h
    }
  if (h == 0) Lp[sb * NROWS + b * Ll + qrow] = lt;
}

// ---------------- combine the NSB S-chunk partials (pure sum: shared max) ----
extern "C" __global__ __launch_bounds__(256)
void comb_kern(const unsigned short* __restrict__ Op,
               const float* __restrict__ Lp, float* __restrict__ Out) {
  const int idx = blockIdx.x * 256 + threadIdx.x;  // one thread per 4 d
  const int row = idx >> 5;
  const int dof = (idx & 31) * 4;
  float den = 0.f;
#pragma unroll
  for (int s = 0; s < NSB; ++s) den += Lp[s * NROWS + row];
  float a0 = 0.f, a1 = 0.f, a2 = 0.f, a3 = 0.f;
#pragma unroll
  for (int s = 0; s < NSB; ++s) {
    uint2 v = *(const uint2*)(Op + ((size_t)s * NROWS + row) * Dd + dof);
    a0 += __uint_as_float(v.x << 16);
    a1 += __uint_as_float(v.x & 0xffff0000u);
    a2 += __uint_as_float(v.y << 16);
    a3 += __uint_as_float(v.y & 0xffff0000u);
  }
  const float inv = 1.f / den;
  float4 r; r.x = a0 * inv; r.y = a1 * inv; r.z = a2 * inv; r.w = a3 * inv;
  *(float4*)(Out + (size_t)row * Dd + dof) = r;
}

extern "C" void kernel_launch(void* const* d_in, const int* in_sizes, int n_in,
                              void* d_out, int out_size, void* d_ws, size_t ws_size,
                              hipStream_t stream) {
  const float* Q = (const float*)d_in[0];
  const float* K = (const float*)d_in[1];
  const float* V = (const float*)d_in[2];
  float* Out = (float*)d_out;
  unsigned short* Qn = (unsigned short*)d_ws;                  // 4 MiB
  unsigned short* Kn = Qn + (size_t)NROWS * Dd;                // 4 MiB
  unsigned short* Vt = Kn + (size_t)NROWS * Dd;                // 4 MiB
  unsigned short* Op = Vt + (size_t)Bb * Dd * Ss;              // 16 MiB (bf16 partials)
  float* Lp = (float*)(Op + (size_t)NSB * NROWS * Dd);         // 256 KiB
  hipLaunchKernelGGL(prep_kern, dim3(8192 + 512), dim3(256), 0, stream, Q, K, V, Qn, Kn, Vt);
  hipLaunchKernelGGL(attn_kern, dim3(512), dim3(256), 0, stream, Qn, Kn, Vt, Op, Lp);
  hipLaunchKernelGGL(comb_kern, dim3(2048), dim3(256), 0, stream, Op, Lp, Out);
}